// Round 1
// baseline (1147.487 us; speedup 1.0000x reference)
//
#include <hip/hip_runtime.h>
#include <cstdint>
#include <cstddef>

#define N_TOK 8192
#define DDIM  1024
#define FDIM  4096
#define NEXP  8
#define CAP   1280
#define MPE   2560                 // slot rows per expert (k=0 half then k=1 half)
#define NSLOT (NEXP * MPE)         // 20480

typedef __attribute__((ext_vector_type(8))) __bf16 bf16x8;
typedef __attribute__((ext_vector_type(4))) float  f32x4;

__device__ __forceinline__ unsigned short f2bf(float f) {
    unsigned int u = __float_as_uint(f);
    u += 0x7fffu + ((u >> 16) & 1u);   // RNE (finite inputs)
    return (unsigned short)(u >> 16);
}
__device__ __forceinline__ float bf2f(unsigned short s) {
    return __uint_as_float(((unsigned int)s) << 16);
}

__device__ __forceinline__ void async_cp16(const void* g, void* l) {
    __builtin_amdgcn_global_load_lds(
        (const __attribute__((address_space(1))) unsigned int*)g,
        (__attribute__((address_space(3))) unsigned int*)l, 16, 0, 0);
}

// ---------------- weight pre-convert: fp32 -> bf16 ----------------
// wcomb[e][8192][1024]: row r -> fb=r>>7, half=(r>>6)&1, fi=r&63, feature f=fb*64+fi
__global__ __launch_bounds__(256) void convert_wi_kernel(
    const float* __restrict__ wi_gate, const float* __restrict__ wi_up,
    unsigned short* __restrict__ wcomb)
{
    const int idx = blockIdx.x * 256 + threadIdx.x;   // 8M threads, 8 elems each
    const int d8 = idx & 127;
    const int r  = (idx >> 7) & 8191;
    const int e  = idx >> 20;
    const int f  = (r >> 7) * 64 + (r & 63);
    const float* src = (((r >> 6) & 1) ? wi_up : wi_gate)
                       + ((size_t)(e * FDIM + f) * DDIM + d8 * 8);
    const float4 a = ((const float4*)src)[0];
    const float4 b = ((const float4*)src)[1];
    uint4 o;
    o.x = (unsigned)f2bf(a.x) | ((unsigned)f2bf(a.y) << 16);
    o.y = (unsigned)f2bf(a.z) | ((unsigned)f2bf(a.w) << 16);
    o.z = (unsigned)f2bf(b.x) | ((unsigned)f2bf(b.y) << 16);
    o.w = (unsigned)f2bf(b.z) | ((unsigned)f2bf(b.w) << 16);
    *(uint4*)(wcomb + (size_t)idx * 8) = o;
}

__global__ __launch_bounds__(256) void convert_wo_kernel(
    const float* __restrict__ wo, unsigned short* __restrict__ wo_bf)
{
    const int idx = blockIdx.x * 256 + threadIdx.x;   // 4M threads, 8 elems each
    const float4 a = ((const float4*)(wo + (size_t)idx * 8))[0];
    const float4 b = ((const float4*)(wo + (size_t)idx * 8))[1];
    uint4 o;
    o.x = (unsigned)f2bf(a.x) | ((unsigned)f2bf(a.y) << 16);
    o.y = (unsigned)f2bf(a.z) | ((unsigned)f2bf(a.w) << 16);
    o.z = (unsigned)f2bf(b.x) | ((unsigned)f2bf(b.y) << 16);
    o.w = (unsigned)f2bf(b.z) | ((unsigned)f2bf(b.w) << 16);
    *(uint4*)(wo_bf + (size_t)idx * 8) = o;
}

// ---------------- router: wave-per-token, shuffle reduce ----------------
__global__ __launch_bounds__(256) void router_kernel(
    const float* __restrict__ x, const float* __restrict__ gate_w,
    int* __restrict__ topk_idx, float* __restrict__ topk_w,
    float* __restrict__ stats)
{
    const int wave = threadIdx.x >> 6, lane = threadIdx.x & 63;
    const int n = blockIdx.x * 4 + wave;
    const float4* xp = (const float4*)(x + (size_t)n * DDIM + lane * 16);
    float4 xv[4];
#pragma unroll
    for (int i = 0; i < 4; i++) xv[i] = xp[i];
    float part[NEXP];
#pragma unroll
    for (int e = 0; e < NEXP; e++) {
        const float4* gp = (const float4*)(gate_w + (size_t)e * DDIM + lane * 16);
        float s = 0.f;
#pragma unroll
        for (int i = 0; i < 4; i++) {
            const float4 g = gp[i];
            s += xv[i].x * g.x + xv[i].y * g.y + xv[i].z * g.z + xv[i].w * g.w;
        }
        part[e] = s;
    }
#pragma unroll
    for (int off = 32; off > 0; off >>= 1)
#pragma unroll
        for (int e = 0; e < NEXP; e++) part[e] += __shfl_down(part[e], off);
    if (lane == 0) {
        float p[NEXP];
        float m = -1e30f;
#pragma unroll
        for (int e = 0; e < NEXP; e++) m = fmaxf(m, part[e]);
        float sum = 0.f;
#pragma unroll
        for (int e = 0; e < NEXP; e++) { p[e] = __expf(part[e] - m); sum += p[e]; }
        const float inv = 1.f / sum;
#pragma unroll
        for (int e = 0; e < NEXP; e++) p[e] *= inv;
        const float lse = m + __logf(sum);
        int e1 = 0; float p1 = p[0];
#pragma unroll
        for (int e = 1; e < NEXP; e++) if (p[e] > p1) { p1 = p[e]; e1 = e; }
        int e2 = -1; float p2 = -1.f;
#pragma unroll
        for (int e = 0; e < NEXP; e++) if (e != e1 && p[e] > p2) { p2 = p[e]; e2 = e; }
        const float wsum = p1 + p2;
        topk_idx[n * 2 + 0] = e1; topk_idx[n * 2 + 1] = e2;
        topk_w[n * 2 + 0] = p1 / wsum; topk_w[n * 2 + 1] = p2 / wsum;
        float* sp = stats + (n & 63) * 17;
#pragma unroll
        for (int e = 0; e < NEXP; e++) atomicAdd(sp + e, p[e]);
        atomicAdd(sp + 8 + e1, 1.f);
        atomicAdd(sp + 8 + e2, 1.f);
        atomicAdd(sp + 16, lse * lse);
    }
}

// ---------------- positions: first-come cumsum per (k,e), capacity drop ----------------
// slot layout: slot = (e*2 + kk)*CAP + p
__global__ __launch_bounds__(512) void pos_kernel(
    const int* __restrict__ topk_idx, const float* __restrict__ topk_w,
    int* __restrict__ slot_tok, int* __restrict__ tok2slot, int* __restrict__ gcnt)
{
    __shared__ int cnt[2][NEXP][256];
    const int t = threadIdx.x;
    for (int i = t; i < NSLOT; i += 512) slot_tok[i] = -1;
    const int kk = t >> 8;
    const int c  = t & 255;
    int lc[NEXP];
#pragma unroll
    for (int e = 0; e < NEXP; e++) lc[e] = 0;
    const int base_n = c * 32;
    for (int i = 0; i < 32; i++) lc[topk_idx[(base_n + i) * 2 + kk]]++;
#pragma unroll
    for (int e = 0; e < NEXP; e++) cnt[kk][e][c] = lc[e];
    __syncthreads();
    if (t < 16) {                      // 16 serial exclusive scans of 256 chunks
        const int k2 = t >> 3, e = t & 7;
        int run = 0;
        for (int c2 = 0; c2 < 256; c2++) { int v = cnt[k2][e][c2]; cnt[k2][e][c2] = run; run += v; }
        gcnt[e * 2 + k2] = run < CAP ? run : CAP;
    }
    __syncthreads();
    int run[NEXP];
#pragma unroll
    for (int e = 0; e < NEXP; e++) run[e] = cnt[kk][e][c];
    for (int i = 0; i < 32; i++) {
        const int n = base_n + i;
        const int e = topk_idx[n * 2 + kk];
        const int p = run[e]++;
        if (p < CAP) {
            const int slot = (e * 2 + kk) * CAP + p;
            slot_tok[slot] = n;
            tok2slot[n * 2 + kk] = slot;
        } else {
            tok2slot[n * 2 + kk] = -1;
        }
    }
}

// ---------------- dispatch: gather x rows -> bf16 disp ----------------
__global__ __launch_bounds__(128) void dispatch_kernel(
    const float* __restrict__ x, const int* __restrict__ slot_tok,
    unsigned short* __restrict__ disp)
{
    const int slot = blockIdx.x;
    const int t = threadIdx.x;
    const int token = slot_tok[slot];
    uint4 o = make_uint4(0u, 0u, 0u, 0u);
    if (token >= 0) {
        const float4* src = (const float4*)(x + (size_t)token * DDIM + t * 8);
        const float4 a = src[0];
        const float4 b = src[1];
        o.x = (unsigned)f2bf(a.x) | ((unsigned)f2bf(a.y) << 16);
        o.y = (unsigned)f2bf(a.z) | ((unsigned)f2bf(a.w) << 16);
        o.z = (unsigned)f2bf(b.x) | ((unsigned)f2bf(b.y) << 16);
        o.w = (unsigned)f2bf(b.z) | ((unsigned)f2bf(b.w) << 16);
    }
    *(uint4*)(disp + (size_t)slot * DDIM + t * 8) = o;
}

// ---------------- gemm1: act = bf16( silu(disp@Wg^T) * (disp@Wu^T) ) ----------------
// 256x256 tile, BK=32, 512 threads (8 waves 2Mx4N), TRIPLE-buffered LDS (96 KB,
// 1 block/CU), counted-vmcnt pipeline (never vmcnt(0) in steady state), raw
// s_barrier (no __syncthreads drain), per-phase {ds_read | 2x global_load_lds |
// setprio(1) 16xMFMA setprio(0)} interleave. Global-side XOR pre-swizzle keeps
// ds_read_b128 bank-conflict-free (same scheme as before: measured 0 conflicts).
__global__ __launch_bounds__(512, 2) void gemm1_kernel(
    const unsigned short* __restrict__ disp,
    const unsigned short* __restrict__ wcomb,
    const int* __restrict__ gcnt,
    unsigned short* __restrict__ act)
{
    __shared__ __align__(16) unsigned short smem[49152]; // 3 x (A 8192 + B 8192) shorts = 96 KB; epilogue reuses as exch[2][256][68]
    const int b = blockIdx.x;
    const int e    = b / 320;          // 2 kk * 5 mt * 32 nt = 320 per expert
    const int rem  = b % 320;
    const int kk   = rem / 160;
    const int rem2 = rem % 160;
    const int mt = rem2 / 32, nt = rem2 % 32;
    if (mt * 256 >= gcnt[e * 2 + kk]) return;   // fully-empty tile

    const int t = threadIdx.x;
    const int wave = t >> 6, lane = t & 63;
    const unsigned short* Asrc = disp  + (size_t)(e * MPE + kk * CAP + mt * 256) * DDIM;
    const unsigned short* Bsrc = wcomb + (size_t)e * 8192 * DDIM + (size_t)(nt * 256) * DDIM;

    // staging geometry: 512 thr x 16B x 2 loads covers one 256x32 bf16 tile.
    // LDS dest is linear (global_load_lds constraint); the XOR swizzle is applied
    // to the GLOBAL source column chunk instead (m173 pattern).
    const int srow = t >> 2;                                   // 0..127 (l=0), +128 (l=1)
    const int qg   = (((t & 3) ^ ((srow >> 1) & 3)) * 8);      // (srow+128)>>1 &3 identical
    const size_t soff0 = (size_t)srow * DDIM + qg;
    const size_t soff1 = (size_t)(srow + 128) * DDIM + qg;
    const int lb0 = wave * 512;            // LDS wave base, load 0 (shorts)
    const int lb1 = 4096 + wave * 512;     // load 1

#define G1_STAGE_A(c, kt) do { \
        async_cp16(Asrc + soff0 + (size_t)(kt) * 32, &smem[(c) * 16384 + lb0]); \
        async_cp16(Asrc + soff1 + (size_t)(kt) * 32, &smem[(c) * 16384 + lb1]); } while (0)
#define G1_STAGE_B(c, kt) do { \
        async_cp16(Bsrc + soff0 + (size_t)(kt) * 32, &smem[(c) * 16384 + 8192 + lb0]); \
        async_cp16(Bsrc + soff1 + (size_t)(kt) * 32, &smem[(c) * 16384 + 8192 + lb1]); } while (0)

    const int wm = wave >> 2, wn = wave & 3;                   // 2M x 4N waves
    const int lrow = lane & 15, lk = lane >> 4;
    const int lkx = (lk ^ ((lrow >> 1) & 3)) * 8;              // read-side swizzle
    const int aro = (wm * 128 + lrow) * 32 + lkx;              // A-frag i at +i*512
    const int bro = 8192 + (wn * 64 + lrow) * 32 + lkx;        // B-frag j at +j*512

    const f32x4 fzero = {0.f, 0.f, 0.f, 0.f};
    f32x4 acc[8][4];
#pragma unroll
    for (int i = 0; i < 8; i++)
#pragma unroll
        for (int j = 0; j < 4; j++) acc[i][j] = fzero;

    // prologue: tiles 0,1 staged; wait only for tile 0 (vmcnt(4) = tile 1 in flight)
    G1_STAGE_A(0, 0); G1_STAGE_B(0, 0);
    G1_STAGE_A(1, 1); G1_STAGE_B(1, 1);
    asm volatile("s_waitcnt vmcnt(4)" ::: "memory");
    __builtin_amdgcn_s_barrier();

    int cur = 0;
#pragma unroll 1
    for (int kt = 0; kt < 32; ++kt) {
        const int cbase = cur * 16384;
        int cnxt = cur + 2; if (cnxt >= 3) cnxt -= 3;
        const bool pf = (kt + 2 < 32);
        bf16x8 af[4], bfr[4];
        // ---- phase 1: ds_read A0-3 + B0-3 | stage A(kt+2) | 16 MFMA ----
#pragma unroll
        for (int i = 0; i < 4; i++) af[i]  = *(const bf16x8*)&smem[cbase + aro + i * 512];
#pragma unroll
        for (int j = 0; j < 4; j++) bfr[j] = *(const bf16x8*)&smem[cbase + bro + j * 512];
        if (pf) G1_STAGE_A(cnxt, kt + 2);
        __builtin_amdgcn_s_barrier();
        __builtin_amdgcn_s_setprio(1);
#pragma unroll
        for (int i = 0; i < 4; i++)
#pragma unroll
            for (int j = 0; j < 4; j++)
                acc[i][j] = __builtin_amdgcn_mfma_f32_16x16x32_bf16(af[i], bfr[j], acc[i][j], 0, 0, 0);
        __builtin_amdgcn_s_setprio(0);
        __builtin_amdgcn_s_barrier();
        // ---- phase 2: ds_read A4-7 (B reused in regs) | stage B(kt+2) | 16 MFMA ----
        bf16x8 ag[4];
#pragma unroll
        for (int i = 0; i < 4; i++) ag[i] = *(const bf16x8*)&smem[cbase + aro + (i + 4) * 512];
        if (pf) G1_STAGE_B(cnxt, kt + 2);
        __builtin_amdgcn_s_barrier();
        __builtin_amdgcn_s_setprio(1);
#pragma unroll
        for (int i = 0; i < 4; i++)
#pragma unroll
            for (int j = 0; j < 4; j++)
                acc[i + 4][j] = __builtin_amdgcn_mfma_f32_16x16x32_bf16(ag[i], bfr[j], acc[i + 4][j], 0, 0, 0);
        __builtin_amdgcn_s_setprio(0);
        // counted wait: tile kt+1 (issued during kt-1) fully landed; tile kt+2's
        // 4 loads stay in flight. Only the last two iterations drain fully.
        if (pf) asm volatile("s_waitcnt vmcnt(4)" ::: "memory");
        else    asm volatile("s_waitcnt vmcnt(0)" ::: "memory");
        __builtin_amdgcn_s_barrier();
        cur = cur + 1; if (cur == 3) cur = 0;
    }
#undef G1_STAGE_A
#undef G1_STAGE_B

    // epilogue: 256 cols = 2 fb-groups of (gate 64 | up 64). Even-wn waves write
    // gate through LDS (68-short pitch, conflict-free); odd-wn compute silu(g)*u.
    __syncthreads();
    const int g = wn >> 1;
    const int epb = g * 17408;
    if ((wn & 1) == 0) {
#pragma unroll
        for (int i = 0; i < 8; i++)
#pragma unroll
            for (int j = 0; j < 4; j++)
#pragma unroll
                for (int r = 0; r < 4; r++)
                    smem[epb + (wm * 128 + i * 16 + lk * 4 + r) * 68 + j * 16 + lrow] = f2bf(acc[i][j][r]);
    }
    __syncthreads();
    if (wn & 1) {
#pragma unroll
        for (int i = 0; i < 8; i++)
#pragma unroll
            for (int r = 0; r < 4; r++) {
                const int m = wm * 128 + i * 16 + lk * 4 + r;
                const size_t base = (size_t)(e * MPE + kk * CAP + mt * 256 + m) * FDIM + (nt * 2 + g) * 64;
#pragma unroll
                for (int j = 0; j < 4; j++) {
                    const float gv = bf2f(smem[epb + m * 68 + j * 16 + lrow]);
                    const float u  = acc[i][j][r];
                    const float a  = (gv / (1.f + __expf(-gv))) * u;
                    act[base + j * 16 + lrow] = f2bf(a);
                }
            }
    }
}

// ---------------- gemm2: eout[slot] = bf16(act @ wo^T), no atomics ----------------
__global__ __launch_bounds__(256, 3) void gemm2_kernel(
    const unsigned short* __restrict__ act,
    const unsigned short* __restrict__ wo_bf,
    const int* __restrict__ gcnt,
    unsigned short* __restrict__ eout)
{
    __shared__ __align__(16) unsigned short smem[8192]; // A:0..4095  B:4096..8191
    const int b = blockIdx.x;
    const int e   = b / 160;           // 20 mb * 8 nb
    const int rem = b % 160;
    const int mb = rem / 8, nb = rem % 8;
    const int kk = mb / 10;
    if ((mb % 10) * 128 >= gcnt[e * 2 + kk]) return;   // fully-empty tile

    const int t = threadIdx.x;
    const int wave = t >> 6, lane = t & 63;
    const unsigned short* Asrc = act   + (size_t)(e * MPE + mb * 128) * FDIM;
    const unsigned short* Bsrc = wo_bf + (size_t)e * DDIM * FDIM + (size_t)(nb * 128) * FDIM;

    const int arow = t >> 2;
    const int acol = (((t & 3) ^ ((arow >> 1) & 3)) * 8);

    const f32x4 fzero = {0.f, 0.f, 0.f, 0.f};
    f32x4 acc[4][4];
#pragma unroll
    for (int i = 0; i < 4; i++)
#pragma unroll
        for (int j = 0; j < 4; j++) acc[i][j] = fzero;

    const int wm = wave >> 1, wn = wave & 1;
    const int lrow = lane & 15, lk = lane >> 4;
    const int lkx = (lk ^ ((lrow >> 1) & 3)) * 8;

    for (int k0 = 0; k0 < FDIM; k0 += 32) {
        __syncthreads();
        async_cp16(Asrc + (size_t)arow * FDIM + k0 + acol,        &smem[wave * 512]);
        async_cp16(Asrc + (size_t)(arow + 64) * FDIM + k0 + acol, &smem[2048 + wave * 512]);
        async_cp16(Bsrc + (size_t)arow * FDIM + k0 + acol,        &smem[4096 + wave * 512]);
        async_cp16(Bsrc + (size_t)(arow + 64) * FDIM + k0 + acol, &smem[6144 + wave * 512]);
        __syncthreads();
        bf16x8 af[4], bfr[4];
#pragma unroll
        for (int i = 0; i < 4; i++)
            af[i] = *(const bf16x8*)&smem[(wm * 64 + i * 16 + lrow) * 32 + lkx];
#pragma unroll
        for (int j = 0; j < 4; j++)
            bfr[j] = *(const bf16x8*)&smem[4096 + (wn * 64 + j * 16 + lrow) * 32 + lkx];
#pragma unroll
        for (int i = 0; i < 4; i++)
#pragma unroll
            for (int j = 0; j < 4; j++)
                acc[i][j] = __builtin_amdgcn_mfma_f32_16x16x32_bf16(af[i], bfr[j], acc[i][j], 0, 0, 0);
    }
    // epilogue: plain bf16 stores to slot-major eout
#pragma unroll
    for (int i = 0; i < 4; i++)
#pragma unroll
        for (int r = 0; r < 4; r++) {
            const int srow = e * MPE + mb * 128 + wm * 64 + i * 16 + lk * 4 + r;
            const size_t obase = (size_t)srow * DDIM + nb * 128 + wn * 64;
#pragma unroll
            for (int j = 0; j < 4; j++)
                eout[obase + j * 16 + lrow] = f2bf(acc[i][j][r]);
        }
}

// ---------------- combine: out[n] = w0*eout[s0] + w1*eout[s1] ----------------
__global__ __launch_bounds__(256) void combine_kernel(
    const unsigned short* __restrict__ eout,
    const int* __restrict__ tok2slot, const float* __restrict__ topk_w,
    float* __restrict__ out)
{
    const int n = blockIdx.x;
    const int t = threadIdx.x;
    const int s0 = tok2slot[n * 2 + 0], s1 = tok2slot[n * 2 + 1];
    const float w0 = (s0 >= 0) ? topk_w[n * 2 + 0] : 0.f;
    const float w1 = (s1 >= 0) ? topk_w[n * 2 + 1] : 0.f;
    const int a0 = (s0 >= 0) ? s0 : 0;
    const int a1 = (s1 >= 0) ? s1 : 0;
    const uint2 p0 = *(const uint2*)(eout + (size_t)a0 * DDIM + t * 4);
    const uint2 p1 = *(const uint2*)(eout + (size_t)a1 * DDIM + t * 4);
    float4 o;
    o.x = w0 * bf2f((unsigned short)(p0.x & 0xffff)) + w1 * bf2f((unsigned short)(p1.x & 0xffff));
    o.y = w0 * bf2f((unsigned short)(p0.x >> 16))    + w1 * bf2f((unsigned short)(p1.x >> 16));
    o.z = w0 * bf2f((unsigned short)(p0.y & 0xffff)) + w1 * bf2f((unsigned short)(p1.y & 0xffff));
    o.w = w0 * bf2f((unsigned short)(p0.y >> 16))    + w1 * bf2f((unsigned short)(p1.y >> 16));
    *(float4*)(out + (size_t)n * DDIM + t * 4) = o;
}

// ---------------- aux loss ----------------
__global__ void aux_kernel(const float* __restrict__ stats, float* __restrict__ out)
{
    if (threadIdx.x == 0 && blockIdx.x == 0) {
        float ps[NEXP], cn[NEXP], z = 0.f;
#pragma unroll
        for (int e = 0; e < NEXP; e++) { ps[e] = 0.f; cn[e] = 0.f; }
        for (int c = 0; c < 64; c++) {
            const float* sp = stats + c * 17;
#pragma unroll
            for (int e = 0; e < NEXP; e++) { ps[e] += sp[e]; cn[e] += sp[8 + e]; }
            z += sp[16];
        }
        float lb = 0.f;
#pragma unroll
        for (int e = 0; e < NEXP; e++)
            lb += (cn[e] / (2.f * N_TOK)) * (ps[e] / N_TOK);
        const float aux = 0.01f * 8.f * lb + 0.001f * (z / N_TOK);
        out[(size_t)N_TOK * DDIM] = aux;
    }
}

extern "C" void kernel_launch(void* const* d_in, const int* in_sizes, int n_in,
                              void* d_out, int out_size, void* d_ws, size_t ws_size,
                              hipStream_t stream)
{
    (void)in_sizes; (void)n_in; (void)ws_size; (void)out_size;
    const float* x       = (const float*)d_in[0];
    const float* gate_w  = (const float*)d_in[1];
    const float* wi_gate = (const float*)d_in[2];
    const float* wi_up   = (const float*)d_in[3];
    const float* wo      = (const float*)d_in[4];
    float* out = (float*)d_out;
    char* ws = (char*)d_ws;

    // workspace layout (~433 MB)
    int*            topk_idx = (int*)(ws + 0);          //  65536 B
    float*          topk_w   = (float*)(ws + 65536);    //  65536 B
    int*            slot_tok = (int*)(ws + 131072);     //  81920 B
    int*            tok2slot = (int*)(ws + 212992);     //  65536 B
    float*          stats    = (float*)(ws + 278528);   //   4352 B
    int*            gcnt     = (int*)(ws + 282880);     //     64 B
    unsigned short* disp     = (unsigned short*)(ws + 524288);     //  41943040 B
    unsigned short* act      = (unsigned short*)(ws + 42467328);   // 167772160 B
    unsigned short* eout     = (unsigned short*)(ws + 210239488);  //  41943040 B
    unsigned short* wcomb    = (unsigned short*)(ws + 252182528);  // 134217728 B
    unsigned short* wo_bf    = (unsigned short*)(ws + 386400256);  //  67108864 B -> end 453509120

    hipMemsetAsync(stats, 0, 64 * 17 * sizeof(float), stream);

    convert_wi_kernel<<<32768, 256, 0, stream>>>(wi_gate, wi_up, wcomb);
    convert_wo_kernel<<<16384, 256, 0, stream>>>(wo, wo_bf);
    router_kernel<<<N_TOK / 4, 256, 0, stream>>>(x, gate_w, topk_idx, topk_w, stats);
    pos_kernel<<<1, 512, 0, stream>>>(topk_idx, topk_w, slot_tok, tok2slot, gcnt);
    dispatch_kernel<<<NSLOT, 128, 0, stream>>>(x, slot_tok, disp);
    gemm1_kernel<<<NEXP * 2 * 5 * 32, 512, 0, stream>>>(disp, wcomb, gcnt, act);
    gemm2_kernel<<<NEXP * 20 * 8, 256, 0, stream>>>(act, wo_bf, gcnt, eout);
    combine_kernel<<<N_TOK, 256, 0, stream>>>(eout, tok2slot, topk_w, out);
    aux_kernel<<<1, 64, 0, stream>>>(stats, out);
}

// Round 2
// 1100.929 us; speedup vs baseline: 1.0423x; 1.0423x over previous
//
#include <hip/hip_runtime.h>
#include <cstdint>
#include <cstddef>

#define N_TOK 8192
#define DDIM  1024
#define FDIM  4096
#define NEXP  8
#define CAP   1280
#define MPE   2560                 // slot rows per expert (k=0 half then k=1 half)
#define NSLOT (NEXP * MPE)         // 20480

typedef __attribute__((ext_vector_type(8))) __bf16 bf16x8;
typedef __attribute__((ext_vector_type(4))) float  f32x4;

__device__ __forceinline__ unsigned short f2bf(float f) {
    unsigned int u = __float_as_uint(f);
    u += 0x7fffu + ((u >> 16) & 1u);   // RNE (finite inputs)
    return (unsigned short)(u >> 16);
}
__device__ __forceinline__ float bf2f(unsigned short s) {
    return __uint_as_float(((unsigned int)s) << 16);
}

__device__ __forceinline__ void async_cp16(const void* g, void* l) {
    __builtin_amdgcn_global_load_lds(
        (const __attribute__((address_space(1))) unsigned int*)g,
        (__attribute__((address_space(3))) unsigned int*)l, 16, 0, 0);
}

// ---------------- weight pre-convert: fp32 -> bf16 ----------------
// wcomb[e][8192][1024]: row r -> fb=r>>7, half=(r>>6)&1, fi=r&63, feature f=fb*64+fi
__global__ __launch_bounds__(256) void convert_wi_kernel(
    const float* __restrict__ wi_gate, const float* __restrict__ wi_up,
    unsigned short* __restrict__ wcomb)
{
    const int idx = blockIdx.x * 256 + threadIdx.x;   // 8M threads, 8 elems each
    const int d8 = idx & 127;
    const int r  = (idx >> 7) & 8191;
    const int e  = idx >> 20;
    const int f  = (r >> 7) * 64 + (r & 63);
    const float* src = (((r >> 6) & 1) ? wi_up : wi_gate)
                       + ((size_t)(e * FDIM + f) * DDIM + d8 * 8);
    const float4 a = ((const float4*)src)[0];
    const float4 b = ((const float4*)src)[1];
    uint4 o;
    o.x = (unsigned)f2bf(a.x) | ((unsigned)f2bf(a.y) << 16);
    o.y = (unsigned)f2bf(a.z) | ((unsigned)f2bf(a.w) << 16);
    o.z = (unsigned)f2bf(b.x) | ((unsigned)f2bf(b.y) << 16);
    o.w = (unsigned)f2bf(b.z) | ((unsigned)f2bf(b.w) << 16);
    *(uint4*)(wcomb + (size_t)idx * 8) = o;
}

__global__ __launch_bounds__(256) void convert_wo_kernel(
    const float* __restrict__ wo, unsigned short* __restrict__ wo_bf)
{
    const int idx = blockIdx.x * 256 + threadIdx.x;   // 4M threads, 8 elems each
    const float4 a = ((const float4*)(wo + (size_t)idx * 8))[0];
    const float4 b = ((const float4*)(wo + (size_t)idx * 8))[1];
    uint4 o;
    o.x = (unsigned)f2bf(a.x) | ((unsigned)f2bf(a.y) << 16);
    o.y = (unsigned)f2bf(a.z) | ((unsigned)f2bf(a.w) << 16);
    o.z = (unsigned)f2bf(b.x) | ((unsigned)f2bf(b.y) << 16);
    o.w = (unsigned)f2bf(b.z) | ((unsigned)f2bf(b.w) << 16);
    *(uint4*)(wo_bf + (size_t)idx * 8) = o;
}

// ---------------- router: wave-per-token, shuffle reduce ----------------
__global__ __launch_bounds__(256) void router_kernel(
    const float* __restrict__ x, const float* __restrict__ gate_w,
    int* __restrict__ topk_idx, float* __restrict__ topk_w,
    float* __restrict__ stats)
{
    const int wave = threadIdx.x >> 6, lane = threadIdx.x & 63;
    const int n = blockIdx.x * 4 + wave;
    const float4* xp = (const float4*)(x + (size_t)n * DDIM + lane * 16);
    float4 xv[4];
#pragma unroll
    for (int i = 0; i < 4; i++) xv[i] = xp[i];
    float part[NEXP];
#pragma unroll
    for (int e = 0; e < NEXP; e++) {
        const float4* gp = (const float4*)(gate_w + (size_t)e * DDIM + lane * 16);
        float s = 0.f;
#pragma unroll
        for (int i = 0; i < 4; i++) {
            const float4 g = gp[i];
            s += xv[i].x * g.x + xv[i].y * g.y + xv[i].z * g.z + xv[i].w * g.w;
        }
        part[e] = s;
    }
#pragma unroll
    for (int off = 32; off > 0; off >>= 1)
#pragma unroll
        for (int e = 0; e < NEXP; e++) part[e] += __shfl_down(part[e], off);
    if (lane == 0) {
        float p[NEXP];
        float m = -1e30f;
#pragma unroll
        for (int e = 0; e < NEXP; e++) m = fmaxf(m, part[e]);
        float sum = 0.f;
#pragma unroll
        for (int e = 0; e < NEXP; e++) { p[e] = __expf(part[e] - m); sum += p[e]; }
        const float inv = 1.f / sum;
#pragma unroll
        for (int e = 0; e < NEXP; e++) p[e] *= inv;
        const float lse = m + __logf(sum);
        int e1 = 0; float p1 = p[0];
#pragma unroll
        for (int e = 1; e < NEXP; e++) if (p[e] > p1) { p1 = p[e]; e1 = e; }
        int e2 = -1; float p2 = -1.f;
#pragma unroll
        for (int e = 0; e < NEXP; e++) if (e != e1 && p[e] > p2) { p2 = p[e]; e2 = e; }
        const float wsum = p1 + p2;
        topk_idx[n * 2 + 0] = e1; topk_idx[n * 2 + 1] = e2;
        topk_w[n * 2 + 0] = p1 / wsum; topk_w[n * 2 + 1] = p2 / wsum;
        float* sp = stats + (n & 63) * 17;
#pragma unroll
        for (int e = 0; e < NEXP; e++) atomicAdd(sp + e, p[e]);
        atomicAdd(sp + 8 + e1, 1.f);
        atomicAdd(sp + 8 + e2, 1.f);
        atomicAdd(sp + 16, lse * lse);
    }
}

// ---------------- positions: first-come cumsum per (k,e), capacity drop ----------------
// slot layout: slot = (e*2 + kk)*CAP + p
__global__ __launch_bounds__(512) void pos_kernel(
    const int* __restrict__ topk_idx, const float* __restrict__ topk_w,
    int* __restrict__ slot_tok, int* __restrict__ tok2slot, int* __restrict__ gcnt)
{
    __shared__ int cnt[2][NEXP][256];
    const int t = threadIdx.x;
    for (int i = t; i < NSLOT; i += 512) slot_tok[i] = -1;
    const int kk = t >> 8;
    const int c  = t & 255;
    int lc[NEXP];
#pragma unroll
    for (int e = 0; e < NEXP; e++) lc[e] = 0;
    const int base_n = c * 32;
    for (int i = 0; i < 32; i++) lc[topk_idx[(base_n + i) * 2 + kk]]++;
#pragma unroll
    for (int e = 0; e < NEXP; e++) cnt[kk][e][c] = lc[e];
    __syncthreads();
    if (t < 16) {                      // 16 serial exclusive scans of 256 chunks
        const int k2 = t >> 3, e = t & 7;
        int run = 0;
        for (int c2 = 0; c2 < 256; c2++) { int v = cnt[k2][e][c2]; cnt[k2][e][c2] = run; run += v; }
        gcnt[e * 2 + k2] = run < CAP ? run : CAP;
    }
    __syncthreads();
    int run[NEXP];
#pragma unroll
    for (int e = 0; e < NEXP; e++) run[e] = cnt[kk][e][c];
    for (int i = 0; i < 32; i++) {
        const int n = base_n + i;
        const int e = topk_idx[n * 2 + kk];
        const int p = run[e]++;
        if (p < CAP) {
            const int slot = (e * 2 + kk) * CAP + p;
            slot_tok[slot] = n;
            tok2slot[n * 2 + kk] = slot;
        } else {
            tok2slot[n * 2 + kk] = -1;
        }
    }
}

// ---------------- dispatch: gather x rows -> bf16 disp ----------------
__global__ __launch_bounds__(128) void dispatch_kernel(
    const float* __restrict__ x, const int* __restrict__ slot_tok,
    unsigned short* __restrict__ disp)
{
    const int slot = blockIdx.x;
    const int t = threadIdx.x;
    const int token = slot_tok[slot];
    uint4 o = make_uint4(0u, 0u, 0u, 0u);
    if (token >= 0) {
        const float4* src = (const float4*)(x + (size_t)token * DDIM + t * 8);
        const float4 a = src[0];
        const float4 b = src[1];
        o.x = (unsigned)f2bf(a.x) | ((unsigned)f2bf(a.y) << 16);
        o.y = (unsigned)f2bf(a.z) | ((unsigned)f2bf(a.w) << 16);
        o.z = (unsigned)f2bf(b.x) | ((unsigned)f2bf(b.y) << 16);
        o.w = (unsigned)f2bf(b.z) | ((unsigned)f2bf(b.w) << 16);
    }
    *(uint4*)(disp + (size_t)slot * DDIM + t * 8) = o;
}

// ---------------- unified 256x256 MFMA GEMM, register-double-buffered pipeline ----
// Per body (one BK=32 K-tile):
//   vmcnt(4)  : K-tile kt+1's staging landed (kt+2's 4 loads stay in flight)
//   s_barrier : one per body; max wave skew = 1 body => no LDS WAR possible
//   12x ds_read_b128 -> NEXT reg set (frags of kt+1)   } issue-only,
//   4x global_load_lds -> buf[(kt+3)&3] (depth-3)      } stream under MFMA
//   sched_barrier(0)  : pin reads/stages above the MFMA cluster
//   setprio(1); 32x MFMA on CURRENT reg set; setprio(0)
// LDS: 4 buffers x 32 KB = 128 KB (1 block/CU). Global-side XOR pre-swizzle
// keeps ds_read_b128 conflict-free (measured 0 conflicts in prior rounds).
// EPI=1: fused silu(g)*u epilogue via padded LDS exchange (gemm1)
// EPI=0: direct bf16 stores (gemm2)
template<int KDIM, int BROWS, int NT, int EPI>
__global__ __launch_bounds__(512, 2) void gemm256(
    const unsigned short* __restrict__ A,
    const unsigned short* __restrict__ Bw,
    const int* __restrict__ gcnt,
    unsigned short* __restrict__ outp)
{
    constexpr int NKT = KDIM / 32;
    __shared__ __align__(16) unsigned short smem[65536]; // 128 KB
    const int b = blockIdx.x;
    const int e    = b / (2 * 5 * NT);
    const int rem  = b % (2 * 5 * NT);
    const int kk   = rem / (5 * NT);
    const int rem2 = rem % (5 * NT);
    const int mt = rem2 / NT, nt = rem2 % NT;
    if (mt * 256 >= gcnt[e * 2 + kk]) return;   // fully-empty tile

    const int t = threadIdx.x;
    const int wave = t >> 6, lane = t & 63;
    const unsigned short* Asrc = A  + (size_t)(e * MPE + kk * CAP + mt * 256) * KDIM;
    const unsigned short* Bsrc = Bw + ((size_t)e * BROWS + (size_t)nt * 256) * KDIM;

    // staging: 512 thr x 16B covers 128 rows x 32 K; 2 calls per matrix.
    // LDS dest linear (global_load_lds constraint); XOR swizzle on the GLOBAL
    // source chunk; read side applies the same XOR.
    const int srow = t >> 2;                                   // 0..127
    const int qg   = (((t & 3) ^ ((srow >> 1) & 3)) * 8);
    const size_t soff0 = (size_t)srow * KDIM + qg;
    const size_t soff1 = (size_t)(srow + 128) * KDIM + qg;
    const int lb0 = wave * 512, lb1 = 4096 + wave * 512;

#define STG(c, kt) do { \
        const size_t ko_ = (size_t)(kt) * 32; \
        async_cp16(Asrc + soff0 + ko_, &smem[(c) * 16384 + lb0]); \
        async_cp16(Asrc + soff1 + ko_, &smem[(c) * 16384 + lb1]); \
        async_cp16(Bsrc + soff0 + ko_, &smem[(c) * 16384 + 8192 + lb0]); \
        async_cp16(Bsrc + soff1 + ko_, &smem[(c) * 16384 + 8192 + lb1]); } while (0)

    const int wm = wave >> 2, wn = wave & 3;                   // 2M x 4N waves
    const int lrow = lane & 15, lk = lane >> 4;
    const int lkx = (lk ^ ((lrow >> 1) & 3)) * 8;              // read-side swizzle
    const int aro = (wm * 128 + lrow) * 32 + lkx;              // + i*512
    const int bro = 8192 + (wn * 64 + lrow) * 32 + lkx;        // + j*512

    const f32x4 fzero = {0.f, 0.f, 0.f, 0.f};
    f32x4 acc[8][4];
#pragma unroll
    for (int i = 0; i < 8; i++)
#pragma unroll
        for (int j = 0; j < 4; j++) acc[i][j] = fzero;

#define RD(SA, SB, c) do { \
        _Pragma("unroll") for (int i_ = 0; i_ < 8; i_++) \
            SA[i_] = *(const bf16x8*)&smem[(c) * 16384 + aro + i_ * 512]; \
        _Pragma("unroll") for (int j_ = 0; j_ < 4; j_++) \
            SB[j_] = *(const bf16x8*)&smem[(c) * 16384 + bro + j_ * 512]; } while (0)

#define MM(SA, SB) do { \
        __builtin_amdgcn_s_setprio(1); \
        _Pragma("unroll") for (int i_ = 0; i_ < 8; i_++) \
            _Pragma("unroll") for (int j_ = 0; j_ < 4; j_++) \
                acc[i_][j_] = __builtin_amdgcn_mfma_f32_16x16x32_bf16(SA[i_], SB[j_], acc[i_][j_], 0, 0, 0); \
        __builtin_amdgcn_s_setprio(0); } while (0)

#define BODY(kt, CA, CB, NA, NB) do { \
        if ((kt) < NKT - 2) asm volatile("s_waitcnt vmcnt(4)" ::: "memory"); \
        else                asm volatile("s_waitcnt vmcnt(0)" ::: "memory"); \
        __builtin_amdgcn_s_barrier(); \
        if ((kt) + 1 < NKT) RD(NA, NB, ((kt) + 1) & 3); \
        if ((kt) + 3 < NKT) STG(((kt) + 3) & 3, (kt) + 3); \
        __builtin_amdgcn_sched_barrier(0); \
        MM(CA, CB); } while (0)

    // prologue: stage K-tiles 0,1,2 (depth 3); wait only for tile 0
    STG(0, 0); STG(1, 1); STG(2, 2);
    asm volatile("s_waitcnt vmcnt(8)" ::: "memory");
    __builtin_amdgcn_s_barrier();

    bf16x8 afA[8], bfA[4], afB[8], bfB[4];
    RD(afA, bfA, 0);

#pragma unroll 1
    for (int m = 0; m < NKT / 2; m++) {
        BODY(2 * m,     afA, bfA, afB, bfB);
        BODY(2 * m + 1, afB, bfB, afA, bfA);
    }
#undef BODY
#undef MM
#undef RD
#undef STG

    if constexpr (EPI == 1) {
        // epilogue: 256 cols = 2 fb-groups of (gate 64 | up 64). Even-wn waves
        // write gate via LDS (68-short pitch); odd-wn compute silu(g)*u.
        __syncthreads();
        const int g = wn >> 1;
        const int epb = g * 17408;
        if ((wn & 1) == 0) {
#pragma unroll
            for (int i = 0; i < 8; i++)
#pragma unroll
                for (int j = 0; j < 4; j++)
#pragma unroll
                    for (int r = 0; r < 4; r++)
                        smem[epb + (wm * 128 + i * 16 + lk * 4 + r) * 68 + j * 16 + lrow] = f2bf(acc[i][j][r]);
        }
        __syncthreads();
        if (wn & 1) {
#pragma unroll
            for (int i = 0; i < 8; i++)
#pragma unroll
                for (int r = 0; r < 4; r++) {
                    const int mrow = wm * 128 + i * 16 + lk * 4 + r;
                    const size_t base = (size_t)(e * MPE + kk * CAP + mt * 256 + mrow) * FDIM + (nt * 2 + g) * 64;
#pragma unroll
                    for (int j = 0; j < 4; j++) {
                        const float gv = bf2f(smem[epb + mrow * 68 + j * 16 + lrow]);
                        const float u  = acc[i][j][r];
                        const float a  = (gv / (1.f + __expf(-gv))) * u;
                        outp[base + j * 16 + lrow] = f2bf(a);
                    }
                }
        }
    } else {
        // plain bf16 stores to slot-major output (row stride DDIM)
#pragma unroll
        for (int i = 0; i < 8; i++)
#pragma unroll
            for (int r = 0; r < 4; r++) {
                const int orow = e * MPE + kk * CAP + mt * 256 + wm * 128 + i * 16 + lk * 4 + r;
                const size_t obase = (size_t)orow * DDIM + nt * 256 + wn * 64;
#pragma unroll
                for (int j = 0; j < 4; j++)
                    outp[obase + j * 16 + lrow] = f2bf(acc[i][j][r]);
            }
    }
}

// ---------------- combine: out[n] = w0*eout[s0] + w1*eout[s1] ----------------
__global__ __launch_bounds__(256) void combine_kernel(
    const unsigned short* __restrict__ eout,
    const int* __restrict__ tok2slot, const float* __restrict__ topk_w,
    float* __restrict__ out)
{
    const int n = blockIdx.x;
    const int t = threadIdx.x;
    const int s0 = tok2slot[n * 2 + 0], s1 = tok2slot[n * 2 + 1];
    const float w0 = (s0 >= 0) ? topk_w[n * 2 + 0] : 0.f;
    const float w1 = (s1 >= 0) ? topk_w[n * 2 + 1] : 0.f;
    const int a0 = (s0 >= 0) ? s0 : 0;
    const int a1 = (s1 >= 0) ? s1 : 0;
    const uint2 p0 = *(const uint2*)(eout + (size_t)a0 * DDIM + t * 4);
    const uint2 p1 = *(const uint2*)(eout + (size_t)a1 * DDIM + t * 4);
    float4 o;
    o.x = w0 * bf2f((unsigned short)(p0.x & 0xffff)) + w1 * bf2f((unsigned short)(p1.x & 0xffff));
    o.y = w0 * bf2f((unsigned short)(p0.x >> 16))    + w1 * bf2f((unsigned short)(p1.x >> 16));
    o.z = w0 * bf2f((unsigned short)(p0.y & 0xffff)) + w1 * bf2f((unsigned short)(p1.y & 0xffff));
    o.w = w0 * bf2f((unsigned short)(p0.y >> 16))    + w1 * bf2f((unsigned short)(p1.y >> 16));
    *(float4*)(out + (size_t)n * DDIM + t * 4) = o;
}

// ---------------- aux loss ----------------
__global__ void aux_kernel(const float* __restrict__ stats, float* __restrict__ out)
{
    if (threadIdx.x == 0 && blockIdx.x == 0) {
        float ps[NEXP], cn[NEXP], z = 0.f;
#pragma unroll
        for (int e = 0; e < NEXP; e++) { ps[e] = 0.f; cn[e] = 0.f; }
        for (int c = 0; c < 64; c++) {
            const float* sp = stats + c * 17;
#pragma unroll
            for (int e = 0; e < NEXP; e++) { ps[e] += sp[e]; cn[e] += sp[8 + e]; }
            z += sp[16];
        }
        float lb = 0.f;
#pragma unroll
        for (int e = 0; e < NEXP; e++)
            lb += (cn[e] / (2.f * N_TOK)) * (ps[e] / N_TOK);
        const float aux = 0.01f * 8.f * lb + 0.001f * (z / N_TOK);
        out[(size_t)N_TOK * DDIM] = aux;
    }
}

extern "C" void kernel_launch(void* const* d_in, const int* in_sizes, int n_in,
                              void* d_out, int out_size, void* d_ws, size_t ws_size,
                              hipStream_t stream)
{
    (void)in_sizes; (void)n_in; (void)ws_size; (void)out_size;
    const float* x       = (const float*)d_in[0];
    const float* gate_w  = (const float*)d_in[1];
    const float* wi_gate = (const float*)d_in[2];
    const float* wi_up   = (const float*)d_in[3];
    const float* wo      = (const float*)d_in[4];
    float* out = (float*)d_out;
    char* ws = (char*)d_ws;

    // workspace layout (~433 MB)
    int*            topk_idx = (int*)(ws + 0);          //  65536 B
    float*          topk_w   = (float*)(ws + 65536);    //  65536 B
    int*            slot_tok = (int*)(ws + 131072);     //  81920 B
    int*            tok2slot = (int*)(ws + 212992);     //  65536 B
    float*          stats    = (float*)(ws + 278528);   //   4352 B
    int*            gcnt     = (int*)(ws + 282880);     //     64 B
    unsigned short* disp     = (unsigned short*)(ws + 524288);     //  41943040 B
    unsigned short* act      = (unsigned short*)(ws + 42467328);   // 167772160 B
    unsigned short* eout     = (unsigned short*)(ws + 210239488);  //  41943040 B
    unsigned short* wcomb    = (unsigned short*)(ws + 252182528);  // 134217728 B
    unsigned short* wo_bf    = (unsigned short*)(ws + 386400256);  //  67108864 B -> end 453509120

    hipMemsetAsync(stats, 0, 64 * 17 * sizeof(float), stream);

    convert_wi_kernel<<<32768, 256, 0, stream>>>(wi_gate, wi_up, wcomb);
    convert_wo_kernel<<<16384, 256, 0, stream>>>(wo, wo_bf);
    router_kernel<<<N_TOK / 4, 256, 0, stream>>>(x, gate_w, topk_idx, topk_w, stats);
    pos_kernel<<<1, 512, 0, stream>>>(topk_idx, topk_w, slot_tok, tok2slot, gcnt);
    dispatch_kernel<<<NSLOT, 128, 0, stream>>>(x, slot_tok, disp);
    gemm256<1024, 8192, 32, 1><<<NEXP * 2 * 5 * 32, 512, 0, stream>>>(disp, wcomb, gcnt, act);
    gemm256<4096, 1024, 4, 0><<<NEXP * 2 * 5 * 4, 512, 0, stream>>>(act, wo_bf, gcnt, eout);
    combine_kernel<<<N_TOK, 256, 0, stream>>>(eout, tok2slot, topk_w, out);
    aux_kernel<<<1, 64, 0, stream>>>(stats, out);
}

// Round 4
// 1049.501 us; speedup vs baseline: 1.0934x; 1.0490x over previous
//
#include <hip/hip_runtime.h>
#include <cstdint>
#include <cstddef>

#define N_TOK 8192
#define DDIM  1024
#define FDIM  4096
#define NEXP  8
#define CAP   1280
#define MPE   2560                 // slot rows per expert (k=0 half then k=1 half)
#define NSLOT (NEXP * MPE)         // 20480

typedef __attribute__((ext_vector_type(8))) __bf16 bf16x8;
typedef __attribute__((ext_vector_type(4))) float  f32x4;

__device__ __forceinline__ unsigned short f2bf(float f) {
    unsigned int u = __float_as_uint(f);
    u += 0x7fffu + ((u >> 16) & 1u);   // RNE (finite inputs)
    return (unsigned short)(u >> 16);
}
__device__ __forceinline__ float bf2f(unsigned short s) {
    return __uint_as_float(((unsigned int)s) << 16);
}

__device__ __forceinline__ void async_cp16(const void* g, void* l) {
    __builtin_amdgcn_global_load_lds(
        (const __attribute__((address_space(1))) unsigned int*)g,
        (__attribute__((address_space(3))) unsigned int*)l, 16, 0, 0);
}

// ---------------- weight pre-convert: fp32 -> bf16 ----------------
// wcomb[e][8192][1024]: row r -> fb=r>>7, half=(r>>6)&1, fi=r&63, feature f=fb*64+fi
__global__ __launch_bounds__(256) void convert_wi_kernel(
    const float* __restrict__ wi_gate, const float* __restrict__ wi_up,
    unsigned short* __restrict__ wcomb)
{
    const int idx = blockIdx.x * 256 + threadIdx.x;   // 8M threads, 8 elems each
    const int d8 = idx & 127;
    const int r  = (idx >> 7) & 8191;
    const int e  = idx >> 20;
    const int f  = (r >> 7) * 64 + (r & 63);
    const float* src = (((r >> 6) & 1) ? wi_up : wi_gate)
                       + ((size_t)(e * FDIM + f) * DDIM + d8 * 8);
    const float4 a = ((const float4*)src)[0];
    const float4 b = ((const float4*)src)[1];
    uint4 o;
    o.x = (unsigned)f2bf(a.x) | ((unsigned)f2bf(a.y) << 16);
    o.y = (unsigned)f2bf(a.z) | ((unsigned)f2bf(a.w) << 16);
    o.z = (unsigned)f2bf(b.x) | ((unsigned)f2bf(b.y) << 16);
    o.w = (unsigned)f2bf(b.z) | ((unsigned)f2bf(b.w) << 16);
    *(uint4*)(wcomb + (size_t)idx * 8) = o;
}

__global__ __launch_bounds__(256) void convert_wo_kernel(
    const float* __restrict__ wo, unsigned short* __restrict__ wo_bf)
{
    const int idx = blockIdx.x * 256 + threadIdx.x;   // 4M threads, 8 elems each
    const float4 a = ((const float4*)(wo + (size_t)idx * 8))[0];
    const float4 b = ((const float4*)(wo + (size_t)idx * 8))[1];
    uint4 o;
    o.x = (unsigned)f2bf(a.x) | ((unsigned)f2bf(a.y) << 16);
    o.y = (unsigned)f2bf(a.z) | ((unsigned)f2bf(a.w) << 16);
    o.z = (unsigned)f2bf(b.x) | ((unsigned)f2bf(b.y) << 16);
    o.w = (unsigned)f2bf(b.z) | ((unsigned)f2bf(b.w) << 16);
    *(uint4*)(wo_bf + (size_t)idx * 8) = o;
}

// ---------------- router: wave-per-token, shuffle reduce ----------------
__global__ __launch_bounds__(256) void router_kernel(
    const float* __restrict__ x, const float* __restrict__ gate_w,
    int* __restrict__ topk_idx, float* __restrict__ topk_w,
    float* __restrict__ stats)
{
    const int wave = threadIdx.x >> 6, lane = threadIdx.x & 63;
    const int n = blockIdx.x * 4 + wave;
    const float4* xp = (const float4*)(x + (size_t)n * DDIM + lane * 16);
    float4 xv[4];
#pragma unroll
    for (int i = 0; i < 4; i++) xv[i] = xp[i];
    float part[NEXP];
#pragma unroll
    for (int e = 0; e < NEXP; e++) {
        const float4* gp = (const float4*)(gate_w + (size_t)e * DDIM + lane * 16);
        float s = 0.f;
#pragma unroll
        for (int i = 0; i < 4; i++) {
            const float4 g = gp[i];
            s += xv[i].x * g.x + xv[i].y * g.y + xv[i].z * g.z + xv[i].w * g.w;
        }
        part[e] = s;
    }
#pragma unroll
    for (int off = 32; off > 0; off >>= 1)
#pragma unroll
        for (int e = 0; e < NEXP; e++) part[e] += __shfl_down(part[e], off);
    if (lane == 0) {
        float p[NEXP];
        float m = -1e30f;
#pragma unroll
        for (int e = 0; e < NEXP; e++) m = fmaxf(m, part[e]);
        float sum = 0.f;
#pragma unroll
        for (int e = 0; e < NEXP; e++) { p[e] = __expf(part[e] - m); sum += p[e]; }
        const float inv = 1.f / sum;
#pragma unroll
        for (int e = 0; e < NEXP; e++) p[e] *= inv;
        const float lse = m + __logf(sum);
        int e1 = 0; float p1 = p[0];
#pragma unroll
        for (int e = 1; e < NEXP; e++) if (p[e] > p1) { p1 = p[e]; e1 = e; }
        int e2 = -1; float p2 = -1.f;
#pragma unroll
        for (int e = 0; e < NEXP; e++) if (e != e1 && p[e] > p2) { p2 = p[e]; e2 = e; }
        const float wsum = p1 + p2;
        topk_idx[n * 2 + 0] = e1; topk_idx[n * 2 + 1] = e2;
        topk_w[n * 2 + 0] = p1 / wsum; topk_w[n * 2 + 1] = p2 / wsum;
        float* sp = stats + (n & 63) * 17;
#pragma unroll
        for (int e = 0; e < NEXP; e++) atomicAdd(sp + e, p[e]);
        atomicAdd(sp + 8 + e1, 1.f);
        atomicAdd(sp + 8 + e2, 1.f);
        atomicAdd(sp + 16, lse * lse);
    }
}

// ---------------- positions: first-come cumsum per (k,e), capacity drop ----------------
// slot layout: slot = (e*2 + kk)*CAP + p
__global__ __launch_bounds__(512) void pos_kernel(
    const int* __restrict__ topk_idx, const float* __restrict__ topk_w,
    int* __restrict__ slot_tok, int* __restrict__ tok2slot, int* __restrict__ gcnt)
{
    __shared__ int cnt[2][NEXP][256];
    const int t = threadIdx.x;
    for (int i = t; i < NSLOT; i += 512) slot_tok[i] = -1;
    const int kk = t >> 8;
    const int c  = t & 255;
    int lc[NEXP];
#pragma unroll
    for (int e = 0; e < NEXP; e++) lc[e] = 0;
    const int base_n = c * 32;
    for (int i = 0; i < 32; i++) lc[topk_idx[(base_n + i) * 2 + kk]]++;
#pragma unroll
    for (int e = 0; e < NEXP; e++) cnt[kk][e][c] = lc[e];
    __syncthreads();
    if (t < 16) {                      // 16 serial exclusive scans of 256 chunks
        const int k2 = t >> 3, e = t & 7;
        int run = 0;
        for (int c2 = 0; c2 < 256; c2++) { int v = cnt[k2][e][c2]; cnt[k2][e][c2] = run; run += v; }
        gcnt[e * 2 + k2] = run < CAP ? run : CAP;
    }
    __syncthreads();
    int run[NEXP];
#pragma unroll
    for (int e = 0; e < NEXP; e++) run[e] = cnt[kk][e][c];
    for (int i = 0; i < 32; i++) {
        const int n = base_n + i;
        const int e = topk_idx[n * 2 + kk];
        const int p = run[e]++;
        if (p < CAP) {
            const int slot = (e * 2 + kk) * CAP + p;
            slot_tok[slot] = n;
            tok2slot[n * 2 + kk] = slot;
        } else {
            tok2slot[n * 2 + kk] = -1;
        }
    }
}

// ---------------- dispatch: gather x rows -> bf16 disp ----------------
__global__ __launch_bounds__(128) void dispatch_kernel(
    const float* __restrict__ x, const int* __restrict__ slot_tok,
    unsigned short* __restrict__ disp)
{
    const int slot = blockIdx.x;
    const int t = threadIdx.x;
    const int token = slot_tok[slot];
    uint4 o = make_uint4(0u, 0u, 0u, 0u);
    if (token >= 0) {
        const float4* src = (const float4*)(x + (size_t)token * DDIM + t * 8);
        const float4 a = src[0];
        const float4 b = src[1];
        o.x = (unsigned)f2bf(a.x) | ((unsigned)f2bf(a.y) << 16);
        o.y = (unsigned)f2bf(a.z) | ((unsigned)f2bf(a.w) << 16);
        o.z = (unsigned)f2bf(b.x) | ((unsigned)f2bf(b.y) << 16);
        o.w = (unsigned)f2bf(b.z) | ((unsigned)f2bf(b.w) << 16);
    }
    *(uint4*)(disp + (size_t)slot * DDIM + t * 8) = o;
}

// ---------------- 256x256 MFMA GEMM: m201-faithful 4-phase/K-tile schedule ----
// BK=64, 8 waves (2M x 4N), per-wave out 128x64, acc[8][4].
// LDS: 2 buffers x 64 KB (A 256x64 | B 256x64 bf16). Half-tile = 128 rows x 64 K
// = 16 KB = 512thr x 16B x 2 loads.
// Per K-tile kt (buffer c = kt&1), 4 phases, each:
//   { ds_read subtile ; stage 1 half-tile ; barrier ; lgkmcnt(0) ;
//     sched_barrier(0) ; setprio(1) ; 16 MFMA ; setprio(0) ; [P4: vmcnt] ; barrier }
// Phase map (reads from buf c / MFMA quadrant / stage target):
//   P1: read a(i0-3)+b(j0-1) (12) | MFMA i0-3 x j0-1 | stage A0(kt+1)->buf c^1
//   P2: read b(j2-3)          (4) | MFMA i0-3 x j2-3 | stage A1(kt+1)->buf c^1
//   P3: read a(i4-7)          (8) | MFMA i4-7 x j0-1 | stage B0(kt+2)->buf c
//   P4: (none)                    | MFMA i4-7 x j2-3 | stage B1(kt+2)->buf c
// Hazard ledger: A-half regions of buf c^1 last read at kt-1 P3 (lgkm-complete
// before kt-1 P3's 2nd barrier) -> P1/P2 stage safe. B regions of buf c fully
// read by P2 (complete before P2's 2nd barrier) -> P3/P4 stage safe.
// vmcnt(4) at P4: drains through A1(kt+1) (issued P2), keeps B0,B1(kt+2)
// (4 wave-instrs) in flight -- never 0 mid-loop.
// Swizzle: global chunk q' = q ^ ((row>>1)&7) pre-applied on SOURCE (LDS linear),
// read applies same XOR: 16-lane frag read spreads 2 lanes/bank (free).
template<int KDIM, int BROWS, int NT, int EPI>
__global__ __launch_bounds__(512, 2) void gemm256(
    const unsigned short* __restrict__ A,
    const unsigned short* __restrict__ Bw,
    const int* __restrict__ gcnt,
    unsigned short* __restrict__ outp)
{
    constexpr int NKT = KDIM / 64;
    __shared__ __align__(16) unsigned short smem[65536]; // 128 KB
    const int b = blockIdx.x;
    const int e    = b / (2 * 5 * NT);
    const int rem  = b % (2 * 5 * NT);
    const int kk   = rem / (5 * NT);
    const int rem2 = rem % (5 * NT);
    const int mt = rem2 / NT, nt = rem2 % NT;
    if (mt * 256 >= gcnt[e * 2 + kk]) return;   // fully-empty tile

    const int t = threadIdx.x;
    const int wave = t >> 6, lane = t & 63;
    const unsigned short* Asrc = A  + (size_t)(e * MPE + kk * CAP + mt * 256) * KDIM;
    const unsigned short* Bsrc = Bw + ((size_t)e * BROWS + (size_t)nt * 256) * KDIM;

    // ---- staging geometry (per half-tile: 128 rows x 64 K, 2 loads/thread) ----
    const int rl = t >> 3;                         // 0..63 (load1: +64)
    const int q  = t & 7;                          // 16B chunk within 128B row
    const int qx = (q ^ ((rl >> 1) & 7)) * 8;      // pre-swizzled source chunk (elems)
    const size_t sbase = (size_t)rl * KDIM + qx;   // + h*128*KDIM + kt*64; load1 +64*KDIM
    const int dbase = wave * 512;                  // LDS dest (shorts); load1 +4096

    // mat: 0 = A (LDS offset 0), 1 = B (LDS offset 16384 shorts)
#define STG_H(c, mat, h, kt) do { \
        const unsigned short* s_ = ((mat) ? Bsrc : Asrc) + (size_t)(h) * 128 * KDIM + (size_t)(kt) * 64 + sbase; \
        unsigned short* d_ = &smem[(c) * 32768 + (mat) * 16384 + (h) * 8192 + dbase]; \
        async_cp16(s_, d_); \
        async_cp16(s_ + (size_t)64 * KDIM, d_ + 4096); } while (0)

    // ---- fragment read geometry ----
    const int wm = wave >> 2, wn = wave & 3;       // 2M x 4N waves
    const int lrow = lane & 15, lk = lane >> 4;
    const int xr   = (lrow >> 1) & 7;              // read-side XOR (row bits)
    const int aoff = (wm * 128 + lrow) * 64;       // A row base (shorts)
    const int boff = 16384 + (wn * 64 + lrow) * 64;// B row base (shorts)
    const int k0x = ((0 + lk) ^ xr) * 8;           // ks=0 chunk
    const int k1x = ((4 + lk) ^ xr) * 8;           // ks=1 chunk

    bf16x8 a[4][2], bf[4][2];
    const f32x4 fzero = {0.f, 0.f, 0.f, 0.f};
    f32x4 acc[8][4];
#pragma unroll
    for (int i = 0; i < 8; i++)
#pragma unroll
        for (int j = 0; j < 4; j++) acc[i][j] = fzero;

#define RD_A(c, ib) do { \
        _Pragma("unroll") for (int i_ = 0; i_ < 4; i_++) { \
            a[i_][0] = *(const bf16x8*)&smem[(c) * 32768 + aoff + ((ib) + i_) * 1024 + k0x]; \
            a[i_][1] = *(const bf16x8*)&smem[(c) * 32768 + aoff + ((ib) + i_) * 1024 + k1x]; } } while (0)
#define RD_B(c, jb) do { \
        _Pragma("unroll") for (int j_ = 0; j_ < 2; j_++) { \
            bf[(jb) + j_][0] = *(const bf16x8*)&smem[(c) * 32768 + boff + ((jb) + j_) * 1024 + k0x]; \
            bf[(jb) + j_][1] = *(const bf16x8*)&smem[(c) * 32768 + boff + ((jb) + j_) * 1024 + k1x]; } } while (0)
#define MM16(ib, jb) do { \
        _Pragma("unroll") for (int ks_ = 0; ks_ < 2; ks_++) \
        _Pragma("unroll") for (int i_ = 0; i_ < 4; i_++) \
        _Pragma("unroll") for (int j_ = 0; j_ < 2; j_++) \
            acc[(ib) + i_][(jb) + j_] = __builtin_amdgcn_mfma_f32_16x16x32_bf16( \
                a[i_][ks_], bf[(jb) + j_][ks_], acc[(ib) + i_][(jb) + j_], 0, 0, 0); } while (0)

#define PH_TOP() do { \
        __builtin_amdgcn_s_barrier(); \
        asm volatile("s_waitcnt lgkmcnt(0)" ::: "memory"); \
        __builtin_amdgcn_sched_barrier(0); \
        __builtin_amdgcn_s_setprio(1); } while (0)
#define PH_BOT() do { \
        __builtin_amdgcn_s_setprio(0); \
        __builtin_amdgcn_s_barrier(); } while (0)

#define KT_BODY(kt, c) do { \
        /* P1 */ \
        RD_A(c, 0); RD_B(c, 0); \
        if ((kt) + 1 < NKT) STG_H((c) ^ 1, 0, 0, (kt) + 1); \
        PH_TOP(); MM16(0, 0); PH_BOT(); \
        /* P2 */ \
        RD_B(c, 2); \
        if ((kt) + 1 < NKT) STG_H((c) ^ 1, 0, 1, (kt) + 1); \
        PH_TOP(); MM16(0, 2); PH_BOT(); \
        /* P3 */ \
        RD_A(c, 4); \
        if ((kt) + 2 < NKT) STG_H(c, 1, 0, (kt) + 2); \
        PH_TOP(); MM16(4, 0); PH_BOT(); \
        /* P4 */ \
        if ((kt) + 2 < NKT) STG_H(c, 1, 1, (kt) + 2); \
        PH_TOP(); MM16(4, 2); \
        __builtin_amdgcn_s_setprio(0); \
        if ((kt) + 2 < NKT) asm volatile("s_waitcnt vmcnt(4)" ::: "memory"); \
        else                asm volatile("s_waitcnt vmcnt(0)" ::: "memory"); \
        __builtin_amdgcn_s_barrier(); } while (0)

    // prologue: tile0 all 4 halves -> buf0; tile1 B halves -> buf1 (A halves of
    // tile1 staged in kt=0 P1/P2). vmcnt(4): tile0's 8 wave-instrs drained,
    // tile1's B (4) stay in flight.
    STG_H(0, 0, 0, 0); STG_H(0, 0, 1, 0); STG_H(0, 1, 0, 0); STG_H(0, 1, 1, 0);
    STG_H(1, 1, 0, 1); STG_H(1, 1, 1, 1);
    asm volatile("s_waitcnt vmcnt(4)" ::: "memory");
    __builtin_amdgcn_s_barrier();

#pragma unroll 1
    for (int m2 = 0; m2 < NKT / 2; ++m2) {
        KT_BODY(2 * m2, 0);
        KT_BODY(2 * m2 + 1, 1);
    }
#undef KT_BODY
#undef PH_TOP
#undef PH_BOT
#undef MM16
#undef RD_A
#undef RD_B
#undef STG_H

    if constexpr (EPI == 1) {
        // epilogue: 256 cols = 2 fb-groups of (gate 64 | up 64). Even-wn waves
        // write gate via LDS (68-short pitch); odd-wn compute silu(g)*u.
        __syncthreads();
        const int g = wn >> 1;
        const int epb = g * 17408;
        if ((wn & 1) == 0) {
#pragma unroll
            for (int i = 0; i < 8; i++)
#pragma unroll
                for (int j = 0; j < 4; j++)
#pragma unroll
                    for (int r = 0; r < 4; r++)
                        smem[epb + (wm * 128 + i * 16 + lk * 4 + r) * 68 + j * 16 + lrow] = f2bf(acc[i][j][r]);
        }
        __syncthreads();
        if (wn & 1) {
#pragma unroll
            for (int i = 0; i < 8; i++)
#pragma unroll
                for (int r = 0; r < 4; r++) {
                    const int mrow = wm * 128 + i * 16 + lk * 4 + r;
                    const size_t base = (size_t)(e * MPE + kk * CAP + mt * 256 + mrow) * FDIM + (nt * 2 + g) * 64;
#pragma unroll
                    for (int j = 0; j < 4; j++) {
                        const float gv = bf2f(smem[epb + mrow * 68 + j * 16 + lrow]);
                        const float u  = acc[i][j][r];
                        const float aa = (gv / (1.f + __expf(-gv))) * u;
                        outp[base + j * 16 + lrow] = f2bf(aa);
                    }
                }
        }
    } else {
        // plain bf16 stores to slot-major output (row stride DDIM)
#pragma unroll
        for (int i = 0; i < 8; i++)
#pragma unroll
            for (int r = 0; r < 4; r++) {
                const int orow = e * MPE + kk * CAP + mt * 256 + wm * 128 + i * 16 + lk * 4 + r;
                const size_t obase = (size_t)orow * DDIM + nt * 256 + wn * 64;
#pragma unroll
                for (int j = 0; j < 4; j++)
                    outp[obase + j * 16 + lrow] = f2bf(acc[i][j][r]);
            }
    }
}

// ---------------- combine: out[n] = w0*eout[s0] + w1*eout[s1] ----------------
__global__ __launch_bounds__(256) void combine_kernel(
    const unsigned short* __restrict__ eout,
    const int* __restrict__ tok2slot, const float* __restrict__ topk_w,
    float* __restrict__ out)
{
    const int n = blockIdx.x;
    const int t = threadIdx.x;
    const int s0 = tok2slot[n * 2 + 0], s1 = tok2slot[n * 2 + 1];
    const float w0 = (s0 >= 0) ? topk_w[n * 2 + 0] : 0.f;
    const float w1 = (s1 >= 0) ? topk_w[n * 2 + 1] : 0.f;
    const int a0 = (s0 >= 0) ? s0 : 0;
    const int a1 = (s1 >= 0) ? s1 : 0;
    const uint2 p0 = *(const uint2*)(eout + (size_t)a0 * DDIM + t * 4);
    const uint2 p1 = *(const uint2*)(eout + (size_t)a1 * DDIM + t * 4);
    float4 o;
    o.x = w0 * bf2f((unsigned short)(p0.x & 0xffff)) + w1 * bf2f((unsigned short)(p1.x & 0xffff));
    o.y = w0 * bf2f((unsigned short)(p0.x >> 16))    + w1 * bf2f((unsigned short)(p1.x >> 16));
    o.z = w0 * bf2f((unsigned short)(p0.y & 0xffff)) + w1 * bf2f((unsigned short)(p1.y & 0xffff));
    o.w = w0 * bf2f((unsigned short)(p0.y >> 16))    + w1 * bf2f((unsigned short)(p1.y >> 16));
    *(float4*)(out + (size_t)n * DDIM + t * 4) = o;
}

// ---------------- aux loss ----------------
__global__ void aux_kernel(const float* __restrict__ stats, float* __restrict__ out)
{
    if (threadIdx.x == 0 && blockIdx.x == 0) {
        float ps[NEXP], cn[NEXP], z = 0.f;
#pragma unroll
        for (int e = 0; e < NEXP; e++) { ps[e] = 0.f; cn[e] = 0.f; }
        for (int c = 0; c < 64; c++) {
            const float* sp = stats + c * 17;
#pragma unroll
            for (int e = 0; e < NEXP; e++) { ps[e] += sp[e]; cn[e] += sp[8 + e]; }
            z += sp[16];
        }
        float lb = 0.f;
#pragma unroll
        for (int e = 0; e < NEXP; e++)
            lb += (cn[e] / (2.f * N_TOK)) * (ps[e] / N_TOK);
        const float aux = 0.01f * 8.f * lb + 0.001f * (z / N_TOK);
        out[(size_t)N_TOK * DDIM] = aux;
    }
}

extern "C" void kernel_launch(void* const* d_in, const int* in_sizes, int n_in,
                              void* d_out, int out_size, void* d_ws, size_t ws_size,
                              hipStream_t stream)
{
    (void)in_sizes; (void)n_in; (void)ws_size; (void)out_size;
    const float* x       = (const float*)d_in[0];
    const float* gate_w  = (const float*)d_in[1];
    const float* wi_gate = (const float*)d_in[2];
    const float* wi_up   = (const float*)d_in[3];
    const float* wo      = (const float*)d_in[4];
    float* out = (float*)d_out;
    char* ws = (char*)d_ws;

    // workspace layout (~433 MB)
    int*            topk_idx = (int*)(ws + 0);          //  65536 B
    float*          topk_w   = (float*)(ws + 65536);    //  65536 B
    int*            slot_tok = (int*)(ws + 131072);     //  81920 B
    int*            tok2slot = (int*)(ws + 212992);     //  65536 B
    float*          stats    = (float*)(ws + 278528);   //   4352 B
    int*            gcnt     = (int*)(ws + 282880);     //     64 B
    unsigned short* disp     = (unsigned short*)(ws + 524288);     //  41943040 B
    unsigned short* act      = (unsigned short*)(ws + 42467328);   // 167772160 B
    unsigned short* eout     = (unsigned short*)(ws + 210239488);  //  41943040 B
    unsigned short* wcomb    = (unsigned short*)(ws + 252182528);  // 134217728 B
    unsigned short* wo_bf    = (unsigned short*)(ws + 386400256);  //  67108864 B -> end 453509120

    hipMemsetAsync(stats, 0, 64 * 17 * sizeof(float), stream);

    convert_wi_kernel<<<32768, 256, 0, stream>>>(wi_gate, wi_up, wcomb);
    convert_wo_kernel<<<16384, 256, 0, stream>>>(wo, wo_bf);
    router_kernel<<<N_TOK / 4, 256, 0, stream>>>(x, gate_w, topk_idx, topk_w, stats);
    pos_kernel<<<1, 512, 0, stream>>>(topk_idx, topk_w, slot_tok, tok2slot, gcnt);
    dispatch_kernel<<<NSLOT, 128, 0, stream>>>(x, slot_tok, disp);
    gemm256<1024, 8192, 32, 1><<<NEXP * 2 * 5 * 32, 512, 0, stream>>>(disp, wcomb, gcnt, act);
    gemm256<4096, 1024, 4, 0><<<NEXP * 2 * 5 * 4, 512, 0, stream>>>(act, wo_bf, gcnt, eout);
    combine_kernel<<<N_TOK, 256, 0, stream>>>(eout, tok2slot, topk_w, out);
    aux_kernel<<<1, 64, 0, stream>>>(stats, out);
}